// Round 3
// baseline (974.692 us; speedup 1.0000x reference)
//
#include <hip/hip_runtime.h>
#include <math.h>

#define NN 512
#define HH 4
#define EE 256
#define NHH (NN*HH)
#define EPSF 1e-6f

typedef float f32x4 __attribute__((ext_vector_type(4)));

__device__ __forceinline__ float elu1(float t) {
    // elu(t) + 1 : t>0 -> t+1 ; else exp(t)
    return t > 0.0f ? (t + 1.0f) : expf(t);
}

// Phase 1: projections + feature map + Zi update + normalizer.
// R=4 rows/block -> 512 blocks (2 blocks/CU, 8 waves/CU) for latency hiding.
// Thread e owns output feature e.
__global__ __launch_bounds__(256) void la_phase1(
    const float* __restrict__ x, const float* __restrict__ Zi,
    const float* __restrict__ Wq, const float* __restrict__ bq,
    const float* __restrict__ Wk, const float* __restrict__ bk,
    const float* __restrict__ Wv, const float* __restrict__ bv,
    float* __restrict__ zi_new,
    float* __restrict__ kqz_ws, float* __restrict__ kk_ws, float* __restrict__ v_ws)
{
    constexpr int R = 4;
    const int e = threadIdx.x;
    const int row0 = blockIdx.x * R;

    __shared__ float xs[R][EE];
    __shared__ float red[4][R];

    #pragma unroll
    for (int r = 0; r < R; ++r)
        xs[r][e] = x[(size_t)(row0 + r) * EE + e];
    __syncthreads();

    const f32x4* Wq4 = (const f32x4*)Wq + (size_t)e * (EE/4);
    const f32x4* Wk4 = (const f32x4*)Wk + (size_t)e * (EE/4);
    const f32x4* Wv4 = (const f32x4*)Wv + (size_t)e * (EE/4);

    float accq[R], acck[R], accv[R];
    #pragma unroll
    for (int r = 0; r < R; ++r) { accq[r] = 0.f; acck[r] = 0.f; accv[r] = 0.f; }

    #pragma unroll 4
    for (int j = 0; j < EE/4; ++j) {
        f32x4 wq = Wq4[j];
        f32x4 wk = Wk4[j];
        f32x4 wv = Wv4[j];
        #pragma unroll
        for (int r = 0; r < R; ++r) {
            f32x4 xr = ((const f32x4*)xs[r])[j];   // LDS b128 broadcast
            accq[r] += xr.x*wq.x + xr.y*wq.y + xr.z*wq.z + xr.w*wq.w;
            acck[r] += xr.x*wk.x + xr.y*wk.y + xr.z*wk.z + xr.w*wk.w;
            accv[r] += xr.x*wv.x + xr.y*wv.y + xr.z*wv.z + xr.w*wv.w;
        }
    }

    const float bqe = bq[e], bke = bk[e], bve = bv[e];
    const int lane = e & 63, wid = e >> 6;
    float kq[R], zn[R];

    #pragma unroll
    for (int r = 0; r < R; ++r) {
        kq[r]  = elu1(accq[r] + bqe);
        float kkr = elu1(acck[r] + bke);
        acck[r] = kkr;                 // now holds kk
        accv[r] = accv[r] + bve;       // now holds v
        size_t idx = (size_t)(row0 + r) * EE + e;
        zn[r] = Zi[idx] + kkr;
        zi_new[idx] = zn[r];
    }

    // Z = 1/(kq . Zi_new + eps), one per row; block-wide reduce over e.
    #pragma unroll
    for (int r = 0; r < R; ++r) {
        float p = kq[r] * zn[r];
        #pragma unroll
        for (int off = 32; off > 0; off >>= 1) p += __shfl_xor(p, off, 64);
        if (lane == 0) red[wid][r] = p;
    }
    __syncthreads();

    #pragma unroll
    for (int r = 0; r < R; ++r) {
        float s = red[0][r] + red[1][r] + red[2][r] + red[3][r];
        float Z = 1.0f / (s + EPSF);
        size_t idx = (size_t)(row0 + r) * EE + e;
        kqz_ws[idx] = kq[r] * Z;   // fold Z into kq so phase 2 needs no scalar
        kk_ws[idx]  = acck[r];
        v_ws[idx]   = accv[r];
    }
}

// Phase 2: stream Si once. One block per (n,h). 256 threads = 4 waves; each
// wave owns 2 consecutive d-rows per step (2 independent loads in flight
// before any dependent FMA/store; x unroll 4 = 8 loads outstanding).
// Si / Si_new are pure streams with zero reuse -> nontemporal, keeping
// L2/L3 warm for Wo (re-read by all 2048 blocks) and the workspace rows.
__global__ __launch_bounds__(256) void la_phase2(
    const float* __restrict__ Si,
    const float* __restrict__ kqz_ws, const float* __restrict__ kk_ws,
    const float* __restrict__ v_ws,
    const float* __restrict__ Wo, const float* __restrict__ bo,
    float* __restrict__ out, float* __restrict__ si_new)
{
    const int nh  = blockIdx.x;
    const int tid = threadIdx.x;
    const int mt  = tid & 63;   // which float4 column group (m = mt*4 .. mt*4+3)
    const int dg  = tid >> 6;   // wave id 0..3

    __shared__ float kks[EE];
    __shared__ float kqs[EE];
    __shared__ float Vp[4][EE];
    __shared__ float Vs[EE];

    kks[tid] = kk_ws[(size_t)nh * EE + tid];
    kqs[tid] = kqz_ws[(size_t)nh * EE + tid];
    __syncthreads();

    const f32x4* Si4 = (const f32x4*)Si     + (size_t)nh * (EE*(EE/4));
    f32x4*       So4 = (f32x4*)si_new       + (size_t)nh * (EE*(EE/4));
    const f32x4  v4  = ((const f32x4*)v_ws)[(size_t)nh * (EE/4) + mt];

    float vx = 0.f, vy = 0.f, vz = 0.f, vw = 0.f;
    // wave dg handles rows {8*it + dg*2, 8*it + dg*2 + 1}
    #pragma unroll 4
    for (int it = 0; it < EE/8; ++it) {
        const int d0 = it*8 + dg*2;
        const int d1 = d0 + 1;
        f32x4 s0 = __builtin_nontemporal_load(&Si4[(size_t)d0 * (EE/4) + mt]);
        f32x4 s1 = __builtin_nontemporal_load(&Si4[(size_t)d1 * (EE/4) + mt]);
        const float kk0 = kks[d0], kq0 = kqs[d0];
        const float kk1 = kks[d1], kq1 = kqs[d1];

        s0.x = fmaf(kk0, v4.x, s0.x);
        s0.y = fmaf(kk0, v4.y, s0.y);
        s0.z = fmaf(kk0, v4.z, s0.z);
        s0.w = fmaf(kk0, v4.w, s0.w);
        s1.x = fmaf(kk1, v4.x, s1.x);
        s1.y = fmaf(kk1, v4.y, s1.y);
        s1.z = fmaf(kk1, v4.z, s1.z);
        s1.w = fmaf(kk1, v4.w, s1.w);

        __builtin_nontemporal_store(s0, &So4[(size_t)d0 * (EE/4) + mt]);
        __builtin_nontemporal_store(s1, &So4[(size_t)d1 * (EE/4) + mt]);

        vx = fmaf(kq0, s0.x, vx);
        vy = fmaf(kq0, s0.y, vy);
        vz = fmaf(kq0, s0.z, vz);
        vw = fmaf(kq0, s0.w, vw);
        vx = fmaf(kq1, s1.x, vx);
        vy = fmaf(kq1, s1.y, vy);
        vz = fmaf(kq1, s1.z, vz);
        vw = fmaf(kq1, s1.w, vw);
    }

    Vp[dg][mt*4 + 0] = vx;
    Vp[dg][mt*4 + 1] = vy;
    Vp[dg][mt*4 + 2] = vz;
    Vp[dg][mt*4 + 3] = vw;
    __syncthreads();
    Vs[tid] = Vp[0][tid] + Vp[1][tid] + Vp[2][tid] + Vp[3][tid];
    __syncthreads();

    // out[e] = V . Wo[e,:] + bo[e]   (Wo is 256 KB -> L2/L3-resident, and
    // with nt-hinted Si streams it should actually STAY resident now)
    const f32x4* Wo4 = (const f32x4*)Wo + (size_t)tid * (EE/4);
    const f32x4* Vs4 = (const f32x4*)Vs;
    float acc = bo[tid];
    #pragma unroll 8
    for (int j = 0; j < EE/4; ++j) {
        f32x4 w  = Wo4[j];
        f32x4 vv = Vs4[j];
        acc += w.x*vv.x + w.y*vv.y + w.z*vv.z + w.w*vv.w;
    }
    out[(size_t)nh * EE + tid] = acc;
}

extern "C" void kernel_launch(void* const* d_in, const int* in_sizes, int n_in,
                              void* d_out, int out_size, void* d_ws, size_t ws_size,
                              hipStream_t stream) {
    const float* x  = (const float*)d_in[0];
    const float* Si = (const float*)d_in[1];
    const float* Zi = (const float*)d_in[2];
    const float* Wq = (const float*)d_in[3];
    const float* bq = (const float*)d_in[4];
    const float* Wk = (const float*)d_in[5];
    const float* bk = (const float*)d_in[6];
    const float* Wv = (const float*)d_in[7];
    const float* bv = (const float*)d_in[8];
    const float* Wo = (const float*)d_in[9];
    const float* bo = (const float*)d_in[10];

    float* out_p   = (float*)d_out;                              // (N,H,E)
    float* si_new  = out_p  + (size_t)NHH * EE;                  // (N,H,E,E)
    float* zi_new  = si_new + (size_t)NHH * EE * EE;             // (N,H,E)

    float* kqz_ws = (float*)d_ws;                // (NH,E) kq * Z
    float* kk_ws  = kqz_ws + (size_t)NHH * EE;   // (NH,E)
    float* v_ws   = kk_ws  + (size_t)NHH * EE;   // (NH,E)

    la_phase1<<<NHH/4, 256, 0, stream>>>(x, Zi, Wq, bq, Wk, bk, Wv, bv,
                                         zi_new, kqz_ws, kk_ws, v_ws);
    la_phase2<<<NHH, 256, 0, stream>>>(Si, kqz_ws, kk_ws, v_ws, Wo, bo,
                                       out_p, si_new);
}